// Round 5
// baseline (28.700 us; speedup 1.0000x reference)
//
#include <hip/hip_runtime.h>
#include <math.h>

#define NIMG 16
#define H 512
#define W 512
#define ORI 10
#define TS 43          // LDS row stride: 42 cols + 1 pad (43%32=11 -> <=2-way, free)

// ---------------- Fused HOG: cells + 2x2 block normalize in ONE kernel ----
// Each block owns a 4x4 patch of output windows (wr,wc in [b*4, b*4+4)),
// computes the 5x5 cells covering them (cell-halo 1, ~1.56x redundant),
// then writes normalized float4 outputs directly. No scratch, no 2nd kernel.
// grid (16,16,16) = 4096 blocks, 256 threads.
__global__ __launch_bounds__(256) void hog_fused_k(const float* __restrict__ img,
                                                   float* __restrict__ out) {
    __shared__ float Tl[40 * TS];      // vertically filtered a+2b+c
    __shared__ float Ul[40 * TS];      // a-c
    __shared__ float hist[25 * 11];    // 25 cells x 10 bins (stride 11)
    const int n  = blockIdx.z;
    const int W0 = blockIdx.y * 4;     // first owned window/cell row
    const int C0 = blockIdx.x * 4;
    const float* im = img + (size_t)n * (H * W);
    const int tid = threadIdx.x;

    // ---- stage T/U for pixel rows [W0*8, W0*8+40), cols [C0*8-1, C0*8+41) ----
    // phase A: issue all 21 loads (latency paid once)
    float va[7], vb[7], vc[7];
    int off[7];
    #pragma unroll
    for (int k = 0; k < 7; ++k) {
        int e = tid + k * 256;
        int r = e / 42, c = e - r * 42;          // const-div -> magic mul
        bool ok = (e < 40 * 42);
        int grow = W0 * 8 + r;                   // can exceed 511 at by=15
        int gcol = C0 * 8 + c - 1;
        bool cin = ok && ((unsigned)grow < (unsigned)H)
                      && ((unsigned)gcol < (unsigned)W);
        const float* p = im + (size_t)grow * W + gcol;
        va[k] = (cin && grow >= 1)    ? p[-W] : 0.0f;
        vb[k] =  cin                  ? p[0]  : 0.0f;
        vc[k] = (cin && grow < H - 1) ? p[W]  : 0.0f;
        off[k] = r * TS + c;
    }
    // phase B: filter + LDS store
    #pragma unroll
    for (int k = 0; k < 7; ++k) {
        if (tid + k * 256 < 40 * 42) {
            Tl[off[k]] = va[k] + 2.0f * vb[k] + vc[k];
            Ul[off[k]] = va[k] - vc[k];
        }
    }
    __syncthreads();

    // ---- cells: 25 cells x 8 pixel-rows = 200 tasks ----
    if (tid < 200) {
        const int ci  = tid >> 3;      // 0..24
        const int sub = tid & 7;       // pixel row within cell
        const int lr = ci / 5, lc = ci - lr * 5;
        if ((W0 + lr) < 64 && (C0 + lc) < 64) {   // uniform per 8-lane group
            const int base = (lr * 8 + sub) * TS + lc * 8;
            float t[10], u[10];
            #pragma unroll
            for (int j = 0; j < 10; ++j) { t[j] = Tl[base + j]; u[j] = Ul[base + j]; }

            float T[11];
            #pragma unroll
            for (int j = 0; j < 11; ++j) T[j] = 0.0f;

            #pragma unroll
            for (int j = 0; j < 8; ++j) {
                float gx = t[j] - t[j+2];
                float gy = u[j] + 2.0f * u[j+1] + u[j+2];
                float mag = __builtin_amdgcn_sqrtf(gx * gx + gy * gy);
                float wB = 1.0f - mag;
                bool gx0 = (gx == 0.0f);
                bool gy0 = (gy == 0.0f);
                if (gx0 | gy0) wB = 0.0f;    // exact-integer p: floor==ceil, weight 1
                float yv = fabsf(gx);
                float xv = (gx < 0.0f) ? -gy : gy;
                if (gx0) xv = 1.0f;          // all e_j false -> bin0 += 1
                float y1 = yv * 0.9510565163f, y2 = yv * 0.8090169944f,
                      y3 = yv * 0.5877852523f, y4 = yv * 0.3090169944f;
                float x1 = xv * 0.3090169944f, x2 = xv * 0.5877852523f,
                      x3 = xv * 0.8090169944f, x4 = xv * 0.9510565163f;
                bool e1 = (y1 >= x1), e2 = (y2 >= x2), e3 = (y3 >= x3), e4 = (y4 >= x4);
                bool e5 = (xv <= 0.0f);
                bool e6 = (y4 <= -x4), e7 = (y3 <= -x3), e8 = (y2 <= -x2), e9 = (y1 <= -x1);
                // cumulative histogram: slots <= bin get 1, slot bin+1 gets wB
                T[0]  += 1.0f;
                T[1]  += e1 ? 1.0f : wB;
                T[2]  += e2 ? 1.0f : (e1 ? wB : 0.0f);
                T[3]  += e3 ? 1.0f : (e2 ? wB : 0.0f);
                T[4]  += e4 ? 1.0f : (e3 ? wB : 0.0f);
                T[5]  += e5 ? 1.0f : (e4 ? wB : 0.0f);
                T[6]  += e6 ? 1.0f : (e5 ? wB : 0.0f);
                T[7]  += e7 ? 1.0f : (e6 ? wB : 0.0f);
                T[8]  += e8 ? 1.0f : (e7 ? wB : 0.0f);
                T[9]  += e9 ? 1.0f : (e8 ? wB : 0.0f);
                T[10] += e9 ? wB : 0.0f;     // ceil wrap: slot10 -> bin0
            }

            float b[10];
            #pragma unroll
            for (int j = 0; j < 10; ++j) b[j] = T[j] - T[j + 1];
            b[0] += T[10];
            #pragma unroll
            for (int j = 0; j < 10; ++j) {
                float v = b[j];
                v += __shfl_xor(v, 1);
                v += __shfl_xor(v, 2);
                v += __shfl_xor(v, 4);
                b[j] = v;
            }
            if (sub == 0) {
                #pragma unroll
                for (int j = 0; j < 10; ++j)
                    hist[ci * 11 + j] = b[j] * 0.015625f;   // cell mean
            }
        }
    }
    __syncthreads();

    // ---- block windows: 10 ori x 4x4 windows = 160 tasks ----
    if (tid < 160) {
        const int o    = tid >> 4;     // 0..9
        const int widx = tid & 15;
        const int wi = widx >> 2, wj = widx & 3;
        const int wr = W0 + wi, wc = C0 + wj;
        if (wr <= 62 && wc <= 62) {
            const int h00 = (wi * 5 + wj) * 11 + o;
            float c00 = hist[h00], c01 = hist[h00 + 11],
                  c10 = hist[h00 + 55], c11 = hist[h00 + 66];
            float s = (c00 + c01) + (c10 + c11);
            float denom = sqrtf(s * s + 1e-10f);   // sqrt(sum^2 + EPS^2)
            float inv = 1.0f / denom;
            float4 o4;
            o4.x = c00 * inv;
            o4.y = c01 * inv;
            o4.z = c10 * inv;
            o4.w = c11 * inv;
            const int idx = ((n * ORI + o) * 63 + wr) * 63 + wc;
            reinterpret_cast<float4*>(out)[idx] = o4;
        }
    }
}

extern "C" void kernel_launch(void* const* d_in, const int* in_sizes, int n_in,
                              void* d_out, int out_size, void* d_ws, size_t ws_size,
                              hipStream_t stream) {
    (void)in_sizes; (void)n_in; (void)out_size; (void)d_ws; (void)ws_size;
    const float* img = (const float*)d_in[0];   // (16,1,512,512)
    float* out = (float*)d_out;                 // (16, 10*63*63*2*2) f32

    hog_fused_k<<<dim3(16, 16, NIMG), 256, 0, stream>>>(img, out);
}

// Round 6
// 22.040 us; speedup vs baseline: 1.3022x; 1.3022x over previous
//
#include <hip/hip_runtime.h>
#include <math.h>

#define NIMG 16
#define HP 512
#define WP 512
#define ORI 10
#define RS 68              // raw LDS row stride: 66 used + 2 pad, keeps b128 16B-aligned
#define RAWN (34 * RS)     // 2312 floats = 9.0 KB

// ---------------- Kernel 1: per-cell 10-bin HOG histograms ----------------
// Tile 32 rows x 64 cols (4x8 cells); grid (8,16,16)=2048 blocks; 256 threads.
// Raw pixels staged HBM->LDS via buffer_load..lds (no VGPR staging, HW
// bounds-check = free zero padding). One thread per cell-pixel-row (256 tasks,
// full utilization). Register cumulative histogram T[11] via 9 sign tests.
__global__ __launch_bounds__(256, 6) void hog_cells_k(const float* __restrict__ img,
                                                      float* __restrict__ cells) {
    __shared__ float raw[RAWN];
    __shared__ float hist[32 * 11];
    const int n   = blockIdx.z;
    const int by  = blockIdx.y;          // 0..15 : 32-row tile
    const int bx  = blockIdx.x;          // 0..7  : 64-col tile
    const int ty0 = by * 32;
    const int tx0 = bx * 64;
    const float* im = img + (size_t)n * (HP * WP);
    const int tid = threadIdx.x;

    // pre-zero OOB halo lines (border blocks only; covers lanes whose load is
    // exec-masked off or lands out of the buffer bounds)
    if (by == 0  && tid < RS) raw[tid] = 0.0f;
    if (by == 15 && tid < RS) raw[33 * RS + tid] = 0.0f;
    if (bx == 0 && tid < 34) raw[tid * RS] = 0.0f;
    if (bx == 7 && tid < 34) raw[tid * RS + 65] = 0.0f;

#if __has_builtin(__builtin_amdgcn_raw_ptr_buffer_load_lds) && __has_builtin(__builtin_amdgcn_make_buffer_rsrc)
    {
        // SRSRC over this image: OOB lanes (rows -1/512, wrapped cols) load 0
        auto rsrc = __builtin_amdgcn_make_buffer_rsrc((void*)im, (short)0,
                                                      HP * WP * 4, 0x00020000);
        const int wv = tid >> 6;         // wave id (LDS base must be wave-uniform)
        #pragma unroll
        for (int k = 0; k < 10; ++k) {
            int e = k * 256 + tid;       // LDS float slot
            int r = e / RS;
            int c = e - r * RS;
            int gcol = tx0 + c - 1;
            // col-OOB would wrap to another row inside the buffer: mask off
            bool colok = ((unsigned)gcol < (unsigned)WP);
            int voff = ((ty0 + r - 1) * WP + gcol) * 4;   // row-OOB -> buffer OOB -> 0
            if (e < RAWN && colok) {
                __builtin_amdgcn_raw_ptr_buffer_load_lds(
                    rsrc,
                    (__attribute__((address_space(3))) void*)&raw[k * 256 + wv * 64],
                    4, voff, 0, 0, 0);
            }
        }
    }
#else
    for (int e = tid; e < RAWN; e += 256) {
        int r = e / RS, c = e - r * RS;
        int grow = ty0 + r - 1, gcol = tx0 + c - 1;
        bool ok = ((unsigned)grow < (unsigned)HP) && ((unsigned)gcol < (unsigned)WP);
        raw[e] = ok ? im[grow * WP + gcol] : 0.0f;
    }
#endif
    __syncthreads();

    // ---- one thread per cell-pixel-row ----
    const int cell = tid >> 3;           // 0..31 (4 cell-rows x 8 cell-cols)
    const int sub  = tid & 7;
    const int ccy = cell >> 3, ccx = cell & 7;
    const int pr = ccy * 8 + sub;        // pixel row in tile; LDS rows pr..pr+2
    const int cb = ccx * 8;              // LDS col base (16B aligned)

    const int b0 = pr * RS + cb;
    float4 a0 = *(const float4*)&raw[b0],          a1 = *(const float4*)&raw[b0 + 4],
           a2 = *(const float4*)&raw[b0 + 8];
    float4 bb0 = *(const float4*)&raw[b0 + RS],    bb1 = *(const float4*)&raw[b0 + RS + 4],
           bb2 = *(const float4*)&raw[b0 + RS + 8];
    float4 c0 = *(const float4*)&raw[b0 + 2 * RS], c1 = *(const float4*)&raw[b0 + 2 * RS + 4],
           c2 = *(const float4*)&raw[b0 + 2 * RS + 8];
    const float A[12] = {a0.x,a0.y,a0.z,a0.w, a1.x,a1.y,a1.z,a1.w, a2.x,a2.y,a2.z,a2.w};
    const float B[12] = {bb0.x,bb0.y,bb0.z,bb0.w, bb1.x,bb1.y,bb1.z,bb1.w, bb2.x,bb2.y,bb2.z,bb2.w};
    const float C[12] = {c0.x,c0.y,c0.z,c0.w, c1.x,c1.y,c1.z,c1.w, c2.x,c2.y,c2.z,c2.w};

    float t[10], u[10];
    #pragma unroll
    for (int j = 0; j < 10; ++j) {
        t[j] = A[j] + 2.0f * B[j] + C[j];   // vertical [1,2,1]
        u[j] = A[j] - C[j];                 // vertical [1,0,-1]
    }

    float T[11];
    #pragma unroll
    for (int j = 0; j < 11; ++j) T[j] = 0.0f;

    #pragma unroll
    for (int j = 0; j < 8; ++j) {
        float gx = t[j] - t[j+2];
        float gy = u[j] + 2.0f * u[j+1] + u[j+2];
        float mag = __builtin_amdgcn_sqrtf(gx * gx + gy * gy);
        float wB = 1.0f - mag;
        bool gx0 = (gx == 0.0f);
        bool gy0 = (gy == 0.0f);
        if (gx0 | gy0) wB = 0.0f;        // exact-integer p: floor==ceil, weight 1
        float yv = fabsf(gx);
        float xv = (gx < 0.0f) ? -gy : gy;
        if (gx0) xv = 1.0f;              // all e_j false -> bin0 += 1
        float y1 = yv * 0.9510565163f, y2 = yv * 0.8090169944f,
              y3 = yv * 0.5877852523f, y4 = yv * 0.3090169944f;
        float x1 = xv * 0.3090169944f, x2 = xv * 0.5877852523f,
              x3 = xv * 0.8090169944f, x4 = xv * 0.9510565163f;
        bool e1 = (y1 >= x1), e2 = (y2 >= x2), e3 = (y3 >= x3), e4 = (y4 >= x4);
        bool e5 = (xv <= 0.0f);
        bool e6 = (y4 <= -x4), e7 = (y3 <= -x3), e8 = (y2 <= -x2), e9 = (y1 <= -x1);
        // cumulative: slots <= bin get 1 (=mag+wB), slot bin+1 gets wB
        T[0]  += 1.0f;
        T[1]  += e1 ? 1.0f : wB;
        T[2]  += e2 ? 1.0f : (e1 ? wB : 0.0f);
        T[3]  += e3 ? 1.0f : (e2 ? wB : 0.0f);
        T[4]  += e4 ? 1.0f : (e3 ? wB : 0.0f);
        T[5]  += e5 ? 1.0f : (e4 ? wB : 0.0f);
        T[6]  += e6 ? 1.0f : (e5 ? wB : 0.0f);
        T[7]  += e7 ? 1.0f : (e6 ? wB : 0.0f);
        T[8]  += e8 ? 1.0f : (e7 ? wB : 0.0f);
        T[9]  += e9 ? 1.0f : (e8 ? wB : 0.0f);
        T[10] += e9 ? wB : 0.0f;         // ceil wrap: slot10 -> bin0
    }

    // cumulative -> bins; 8-lane shuffle reduce (cell lanes are consecutive)
    float b[10];
    #pragma unroll
    for (int j = 0; j < 10; ++j) b[j] = T[j] - T[j + 1];
    b[0] += T[10];
    #pragma unroll
    for (int j = 0; j < 10; ++j) {
        float v = b[j];
        v += __shfl_xor(v, 1);
        v += __shfl_xor(v, 2);
        v += __shfl_xor(v, 4);
        b[j] = v;
    }
    if (sub == 0) {
        #pragma unroll
        for (int j = 0; j < 10; ++j) hist[cell * 11 + j] = b[j];
    }
    __syncthreads();

    // coalesced cell-mean writeout: 320 values per block
    const int gcy0 = by * 4;
    const int gcx0 = bx * 8;
    for (int i = tid; i < 32 * ORI; i += 256) {
        int bn = i >> 5;          // 0..9
        int cl = i & 31;
        int cyy = cl >> 3, cxx = cl & 7;
        cells[(((size_t)n * ORI + bn) * 64 + gcy0 + cyy) * 64 + (gcx0 + cxx)]
            = hist[cl * 11 + bn] * 0.015625f;
    }
}

// ---------------- Kernel 2: 2x2 block gather + L2 normalize ----------------
__global__ __launch_bounds__(256) void hog_blocks_k(const float* __restrict__ cells,
                                                    float* __restrict__ out) {
    const int total = NIMG * ORI * 63 * 63;
    int idx = blockIdx.x * blockDim.x + threadIdx.x;
    if (idx >= total) return;
    int bc = idx % 63;
    int t  = idx / 63;
    int br = t % 63;
    int no = t / 63;                       // n*ORI + o
    const float* c = cells + (((size_t)no * 64 + br) * 64 + bc);
    float c00 = c[0], c01 = c[1], c10 = c[64], c11 = c[65];
    float s = ((c00 + c01) + (c10 + c11));
    float denom = sqrtf(s * s + 1e-10f);   // sqrt(sum^2 + EPS^2)
    float inv = 1.0f / denom;
    float4 o;
    o.x = c00 * inv;
    o.y = c01 * inv;
    o.z = c10 * inv;
    o.w = c11 * inv;
    reinterpret_cast<float4*>(out)[idx] = o;
}

extern "C" void kernel_launch(void* const* d_in, const int* in_sizes, int n_in,
                              void* d_out, int out_size, void* d_ws, size_t ws_size,
                              hipStream_t stream) {
    (void)in_sizes; (void)n_in; (void)out_size; (void)ws_size;
    const float* img = (const float*)d_in[0];   // (16,1,512,512)
    float* out   = (float*)d_out;               // (16, 10*63*63*2*2) f32
    float* cells = (float*)d_ws;                // (16,10,64,64) f32 scratch

    hog_cells_k<<<dim3(8, 16, NIMG), 256, 0, stream>>>(img, cells);

    const int total = NIMG * ORI * 63 * 63;
    hog_blocks_k<<<(total + 255) / 256, 256, 0, stream>>>(cells, out);
}

// Round 7
// 21.689 us; speedup vs baseline: 1.3232x; 1.0162x over previous
//
#include <hip/hip_runtime.h>
#include <math.h>

#define NIMG 16
#define HP 512
#define WP 512
#define ORI 10
#define RS 68              // LDS row stride: 66 used + 2 pad = 17 float4 slots
#define RAWN (34 * RS)     // 2312 floats = 9.25 KB per tile buffer

// ---- stage one 32-row x 64-col tile (+halo = 34x66) into LDS ----
__device__ __forceinline__ void stage_tile(const float* __restrict__ im,
                                           float* rawbuf, int tyIdx, int bx,
                                           int tid) {
    const int ty0 = tyIdx * 32;
    const int tx0 = bx * 64;
    // pre-zero halo slots whose loads are masked off or OOB
    if (tyIdx == 0  && tid < RS) rawbuf[tid] = 0.0f;
    if (tyIdx == 15 && tid < RS) rawbuf[33 * RS + tid] = 0.0f;
    if (bx == 0 && tid < 34) rawbuf[tid * RS] = 0.0f;
    if (bx == 7 && tid < 34) rawbuf[tid * RS + 65] = 0.0f;
#if __has_builtin(__builtin_amdgcn_raw_ptr_buffer_load_lds) && __has_builtin(__builtin_amdgcn_make_buffer_rsrc)
    auto rsrc = __builtin_amdgcn_make_buffer_rsrc((void*)im, (short)0,
                                                  HP * WP * 4, 0x00020000);
    const int wv = tid >> 6;             // LDS base must be wave-uniform
    #pragma unroll
    for (int k = 0; k < 10; ++k) {
        int e = k * 256 + tid;
        int r = e / RS, c = e - r * RS;
        int gcol = tx0 + c - 1;
        bool colok = ((unsigned)gcol < (unsigned)WP);  // col OOB would wrap rows
        int voff = ((ty0 + r - 1) * WP + gcol) * 4;    // row OOB -> HW bounds -> 0
        if (e < RAWN && colok)
            __builtin_amdgcn_raw_ptr_buffer_load_lds(
                rsrc,
                (__attribute__((address_space(3))) void*)&rawbuf[k * 256 + wv * 64],
                4, voff, 0, 0, 0);
    }
#else
    for (int e = tid; e < RAWN; e += 256) {
        int r = e / RS, c = e - r * RS;
        int grow = ty0 + r - 1, gcol = tx0 + c - 1;
        bool ok = ((unsigned)grow < (unsigned)HP) && ((unsigned)gcol < (unsigned)WP);
        rawbuf[e] = ok ? im[(size_t)grow * WP + gcol] : 0.0f;
    }
#endif
}

// ---- compute 32 cell histograms (one thread per cell-pixel-row) ----
__device__ __forceinline__ void compute_tile(const float* rawbuf, float* hist,
                                             int tid) {
    const int cell = tid >> 3;           // 0..31 (4 cell-rows x 8 cell-cols)
    const int sub  = tid & 7;
    const int ccy = cell >> 3, ccx = cell & 7;
    const int pr = ccy * 8 + sub;        // pixel row; LDS rows pr..pr+2
    const float4* r4 = (const float4*)rawbuf;
    const int s = pr * 17 + ccx * 2;     // float4 slot (16B aligned)
    float4 A0 = r4[s],      A1 = r4[s + 1],  A2 = r4[s + 2];
    float4 B0 = r4[s + 17], B1 = r4[s + 18], B2 = r4[s + 19];
    float4 C0 = r4[s + 34], C1 = r4[s + 35], C2 = r4[s + 36];

    // vertical filters as float4 ops (packed-math friendly)
    float4 t4a = A0 + 2.0f * B0 + C0, t4b = A1 + 2.0f * B1 + C1,
           t4c = A2 + 2.0f * B2 + C2;
    float4 u4a = A0 - C0, u4b = A1 - C1, u4c = A2 - C2;
    const float t[12] = {t4a.x,t4a.y,t4a.z,t4a.w, t4b.x,t4b.y,t4b.z,t4b.w,
                         t4c.x,t4c.y,t4c.z,t4c.w};
    const float u[12] = {u4a.x,u4a.y,u4a.z,u4a.w, u4b.x,u4b.y,u4b.z,u4b.w,
                         u4c.x,u4c.y,u4c.z,u4c.w};

    float T[11];                          // slots 1..10 used; T[0] == 8 statically
    #pragma unroll
    for (int j = 1; j < 11; ++j) T[j] = 0.0f;

    #pragma unroll
    for (int j = 0; j < 8; ++j) {
        float gx = t[j] - t[j + 2];
        float gy = u[j] + 2.0f * u[j + 1] + u[j + 2];
        float mag = __builtin_amdgcn_sqrtf(gx * gx + gy * gy);
        float wB = 1.0f - mag;
        bool gx0 = (gx == 0.0f);
        bool gy0 = (gy == 0.0f);
        if (gx0 | gy0) wB = 0.0f;        // exact-integer p: floor==ceil, weight 1
        float yv = fabsf(gx);
        float xv = (gx < 0.0f) ? -gy : gy;
        if (gx0) xv = 1.0f;              // all e_j false -> bin0 += 1
        float y1 = yv * 0.9510565163f, y2 = yv * 0.8090169944f,
              y3 = yv * 0.5877852523f, y4 = yv * 0.3090169944f;
        float x1 = xv * 0.3090169944f, x2 = xv * 0.5877852523f,
              x3 = xv * 0.8090169944f, x4 = xv * 0.9510565163f;
        bool e1 = (y1 >= x1), e2 = (y2 >= x2), e3 = (y3 >= x3), e4 = (y4 >= x4);
        bool e5 = (xv <= 0.0f);
        bool e6 = (y4 <= -x4), e7 = (y3 <= -x3), e8 = (y2 <= -x2), e9 = (y1 <= -x1);
        // cumulative: slots <= bin get 1 (=mag+wB), slot bin+1 gets wB
        T[1]  += e1 ? 1.0f : wB;
        T[2]  += e2 ? 1.0f : (e1 ? wB : 0.0f);
        T[3]  += e3 ? 1.0f : (e2 ? wB : 0.0f);
        T[4]  += e4 ? 1.0f : (e3 ? wB : 0.0f);
        T[5]  += e5 ? 1.0f : (e4 ? wB : 0.0f);
        T[6]  += e6 ? 1.0f : (e5 ? wB : 0.0f);
        T[7]  += e7 ? 1.0f : (e6 ? wB : 0.0f);
        T[8]  += e8 ? 1.0f : (e7 ? wB : 0.0f);
        T[9]  += e9 ? 1.0f : (e8 ? wB : 0.0f);
        T[10] += e9 ? wB : 0.0f;         // ceil wrap: slot10 -> bin0
    }

    float b[10];
    b[0] = 8.0f - T[1] + T[10];          // T[0] = 8 px statically
    #pragma unroll
    for (int j = 1; j < 10; ++j) b[j] = T[j] - T[j + 1];
    #pragma unroll
    for (int j = 0; j < 10; ++j) {
        float v = b[j];
        v += __shfl_xor(v, 1);
        v += __shfl_xor(v, 2);
        v += __shfl_xor(v, 4);
        b[j] = v;
    }
    if (sub == 0) {
        #pragma unroll
        for (int j = 0; j < 10; ++j) hist[cell * 11 + j] = b[j];
    }
}

__device__ __forceinline__ void writeout_tile(float* __restrict__ cells,
                                              const float* hist, int n,
                                              int tyIdx, int bx, int tid) {
    const int gcy0 = tyIdx * 4;
    const int gcx0 = bx * 8;
    for (int i = tid; i < 32 * ORI; i += 256) {
        int bn = i >> 5;          // 0..9
        int cl = i & 31;
        cells[(((size_t)n * ORI + bn) * 64 + gcy0 + (cl >> 3)) * 64 + gcx0 + (cl & 7)]
            = hist[cl * 11 + bn] * 0.015625f;
    }
}

// ---------------- Kernel 1: two-tile pipelined cells ----------------
// grid (8,8,16) = 1024 blocks = 4 resident blocks/CU (tail-free).
// Tile B's HBM->LDS staging is issued before tile A's compute: latency hides.
__global__ __launch_bounds__(256, 4) void hog_cells_k(const float* __restrict__ img,
                                                      float* __restrict__ cells) {
    __shared__ __align__(16) float raw[2][RAWN];
    __shared__ float hist[32 * 11];
    const int n   = blockIdx.z;
    const int bx  = blockIdx.x;          // 0..7  : 64-col tile
    const int byp = blockIdx.y;          // 0..7  : tile PAIR
    const int tyA = byp * 2, tyB = tyA + 1;
    const float* im = img + (size_t)n * (HP * WP);
    const int tid = threadIdx.x;

    stage_tile(im, raw[0], tyA, bx, tid);
    __syncthreads();                      // A staged
    stage_tile(im, raw[1], tyB, bx, tid); // issue B loads (in flight under A compute)
    compute_tile(raw[0], hist, tid);
    __syncthreads();                      // hist(A) ready; B loads drained here
    writeout_tile(cells, hist, n, tyA, bx, tid);
    __syncthreads();                      // hist(A) consumed
    compute_tile(raw[1], hist, tid);
    __syncthreads();                      // hist(B) ready
    writeout_tile(cells, hist, n, tyB, bx, tid);
}

// ---------------- Kernel 2: 2x2 block gather + L2 normalize ----------------
__global__ __launch_bounds__(256) void hog_blocks_k(const float* __restrict__ cells,
                                                    float* __restrict__ out) {
    const int total = NIMG * ORI * 63 * 63;
    int idx = blockIdx.x * blockDim.x + threadIdx.x;
    if (idx >= total) return;
    int bc = idx % 63;
    int t  = idx / 63;
    int br = t % 63;
    int no = t / 63;                       // n*ORI + o
    const float* c = cells + (((size_t)no * 64 + br) * 64 + bc);
    float c00 = c[0], c01 = c[1], c10 = c[64], c11 = c[65];
    float s = ((c00 + c01) + (c10 + c11));
    float denom = sqrtf(s * s + 1e-10f);   // sqrt(sum^2 + EPS^2)
    float inv = 1.0f / denom;
    float4 o;
    o.x = c00 * inv;
    o.y = c01 * inv;
    o.z = c10 * inv;
    o.w = c11 * inv;
    reinterpret_cast<float4*>(out)[idx] = o;
}

extern "C" void kernel_launch(void* const* d_in, const int* in_sizes, int n_in,
                              void* d_out, int out_size, void* d_ws, size_t ws_size,
                              hipStream_t stream) {
    (void)in_sizes; (void)n_in; (void)out_size; (void)ws_size;
    const float* img = (const float*)d_in[0];   // (16,1,512,512)
    float* out   = (float*)d_out;               // (16, 10*63*63*2*2) f32
    float* cells = (float*)d_ws;                // (16,10,64,64) f32 scratch

    hog_cells_k<<<dim3(8, 8, NIMG), 256, 0, stream>>>(img, cells);

    const int total = NIMG * ORI * 63 * 63;
    hog_blocks_k<<<(total + 255) / 256, 256, 0, stream>>>(cells, out);
}